// Round 1
// baseline (797.634 us; speedup 1.0000x reference)
//
#include <hip/hip_runtime.h>
#include <math.h>

#define BH 128
#define L 512
#define D 128
#define LQ 64

// ---------------------------------------------------------------------------
// Kernel 1: S[b] = Q[b] @ K[b]^T   (unscaled logits)
// grid (8,8,BH), block 256.  64x64 output tile, K-chunks of 32.
// ---------------------------------------------------------------------------
__global__ __launch_bounds__(256) void qk_kernel(const float* __restrict__ Q,
                                                 const float* __restrict__ Km,
                                                 float* __restrict__ S) {
  const int b  = blockIdx.z;
  const int qt = blockIdx.y;
  const int kt = blockIdx.x;
  __shared__ float Qs[64][36];   // pad 36: all read patterns <=2-way (free)
  __shared__ float Ks[64][36];
  const int tid = threadIdx.x;
  const int tx = tid & 15;   // output col group (stride-16)
  const int ty = tid >> 4;   // output row group (stride-16)
  const float* Qb = Q  + ((size_t)b * L + qt * 64) * D;
  const float* Kb = Km + ((size_t)b * L + kt * 64) * D;

  float acc[4][4];
#pragma unroll
  for (int i = 0; i < 4; ++i)
#pragma unroll
    for (int j = 0; j < 4; ++j) acc[i][j] = 0.f;

  const int lrow = tid >> 3;        // 0..31
  const int lcol = (tid & 7) * 4;   // 0..28

  for (int c = 0; c < D; c += 32) {
    *(float4*)&Qs[lrow][lcol]      = *(const float4*)&Qb[lrow * D + c + lcol];
    *(float4*)&Qs[lrow + 32][lcol] = *(const float4*)&Qb[(lrow + 32) * D + c + lcol];
    *(float4*)&Ks[lrow][lcol]      = *(const float4*)&Kb[lrow * D + c + lcol];
    *(float4*)&Ks[lrow + 32][lcol] = *(const float4*)&Kb[(lrow + 32) * D + c + lcol];
    __syncthreads();
#pragma unroll
    for (int kk = 0; kk < 32; kk += 4) {
      float4 a[4], bv[4];
#pragma unroll
      for (int i = 0; i < 4; ++i) a[i]  = *(const float4*)&Qs[ty + 16 * i][kk];
#pragma unroll
      for (int j = 0; j < 4; ++j) bv[j] = *(const float4*)&Ks[tx + 16 * j][kk];
#pragma unroll
      for (int i = 0; i < 4; ++i)
#pragma unroll
        for (int j = 0; j < 4; ++j)
          acc[i][j] += a[i].x * bv[j].x + a[i].y * bv[j].y +
                       a[i].z * bv[j].z + a[i].w * bv[j].w;
    }
    __syncthreads();
  }

  float* Sb = S + (((size_t)b * L + qt * 64) * L) + kt * 64;
#pragma unroll
  for (int i = 0; i < 4; ++i)
#pragma unroll
    for (int j = 0; j < 4; ++j)
      Sb[(size_t)(ty + 16 * i) * L + tx + 16 * j] = acc[i][j];
}

// ---------------------------------------------------------------------------
// Kernel 2: S[b, 448+q, 448+k] += dot(rel[b,q,k,:], Q[b,448+q,:])
// one wave per (b,q,k) dot; block = 4 waves.
// ---------------------------------------------------------------------------
__global__ __launch_bounds__(256) void rel_kernel(const float* __restrict__ R,
                                                  const float* __restrict__ Q,
                                                  float* __restrict__ S) {
  const int gw   = blockIdx.x * 4 + (threadIdx.x >> 6);
  const int lane = threadIdx.x & 63;
  const int k = gw & (LQ - 1);
  const int q = (gw >> 6) & (LQ - 1);
  const int b = gw >> 12;
  const float* r  = R + (((size_t)b * LQ + q) * LQ + k) * D;
  const float* qr = Q + ((size_t)b * L + (L - LQ + q)) * D;
  float2 rv = *(const float2*)&r[lane * 2];
  float2 qv = *(const float2*)&qr[lane * 2];
  float s = rv.x * qv.x + rv.y * qv.y;
#pragma unroll
  for (int off = 32; off > 0; off >>= 1) s += __shfl_xor(s, off, 64);
  if (lane == 0) {
    size_t idx = ((size_t)b * L + (L - LQ + q)) * L + (L - LQ + k);
    S[idx] += s;
  }
}

// ---------------------------------------------------------------------------
// Kernel 3a: lm = log(1 - mask)    (precompute, tiny)
// ---------------------------------------------------------------------------
__global__ void masklog_kernel(const float* __restrict__ mask,
                               float* __restrict__ lm, int n) {
  int i = blockIdx.x * blockDim.x + threadIdx.x;
  if (i < n) lm[i] = logf(1.0f - mask[i]);
}

// ---------------------------------------------------------------------------
// Kernel 3b: row softmax over k (512) with scale + logmask, in place.
// one wave per row, block = 4 waves.
// ---------------------------------------------------------------------------
__global__ __launch_bounds__(256) void softmax_kernel(float* __restrict__ S,
                                                      const float* __restrict__ lm) {
  const int grow = blockIdx.x * 4 + (threadIdx.x >> 6);
  const int lane = threadIdx.x & 63;
  const int b = grow >> 9;           // 512 rows per batch-head
  float* row = S + (size_t)grow * L;
  const float* lmb = lm + (size_t)b * L;
  const float scale = 0.08838834764831845f;  // 1/sqrt(128)

  float4 x0 = *(const float4*)&row[lane * 4];
  float4 x1 = *(const float4*)&row[256 + lane * 4];
  float4 m0 = *(const float4*)&lmb[lane * 4];
  float4 m1 = *(const float4*)&lmb[256 + lane * 4];
  x0.x = x0.x * scale + m0.x;  x0.y = x0.y * scale + m0.y;
  x0.z = x0.z * scale + m0.z;  x0.w = x0.w * scale + m0.w;
  x1.x = x1.x * scale + m1.x;  x1.y = x1.y * scale + m1.y;
  x1.z = x1.z * scale + m1.z;  x1.w = x1.w * scale + m1.w;

  float mx = fmaxf(fmaxf(fmaxf(x0.x, x0.y), fmaxf(x0.z, x0.w)),
                   fmaxf(fmaxf(x1.x, x1.y), fmaxf(x1.z, x1.w)));
#pragma unroll
  for (int off = 32; off > 0; off >>= 1) mx = fmaxf(mx, __shfl_xor(mx, off, 64));

  x0.x = __expf(x0.x - mx);  x0.y = __expf(x0.y - mx);
  x0.z = __expf(x0.z - mx);  x0.w = __expf(x0.w - mx);
  x1.x = __expf(x1.x - mx);  x1.y = __expf(x1.y - mx);
  x1.z = __expf(x1.z - mx);  x1.w = __expf(x1.w - mx);

  float sum = x0.x + x0.y + x0.z + x0.w + x1.x + x1.y + x1.z + x1.w;
#pragma unroll
  for (int off = 32; off > 0; off >>= 1) sum += __shfl_xor(sum, off, 64);
  const float inv = 1.0f / sum;

  x0.x *= inv; x0.y *= inv; x0.z *= inv; x0.w *= inv;
  x1.x *= inv; x1.y *= inv; x1.z *= inv; x1.w *= inv;
  *(float4*)&row[lane * 4]       = x0;
  *(float4*)&row[256 + lane * 4] = x1;
}

// ---------------------------------------------------------------------------
// Kernel 4: out[b] = P[b] (512x512) @ V[b] (512x128)
// grid (8, BH), block 256.  64x128 output tile, K-chunks of 32.
// ---------------------------------------------------------------------------
__global__ __launch_bounds__(256) void pv_kernel(const float* __restrict__ P,
                                                 const float* __restrict__ V,
                                                 float* __restrict__ O) {
  const int b  = blockIdx.y;
  const int qt = blockIdx.x;
  __shared__ float Ps[64][36];
  __shared__ float Vs[32][132];
  const int tid = threadIdx.x;
  const int tx = tid & 15;   // col group: cols tx*8 .. tx*8+7
  const int ty = tid >> 4;   // row group: rows ty + 16*i

  float acc[4][8];
#pragma unroll
  for (int i = 0; i < 4; ++i)
#pragma unroll
    for (int j = 0; j < 8; ++j) acc[i][j] = 0.f;

  const float* Pb = P + ((size_t)b * L + qt * 64) * L;
  const float* Vb = V + (size_t)b * L * D;
  const int lrow = tid >> 3;        // 0..31
  const int lcol = (tid & 7) * 4;   // 0..28
  const int vrow = tid >> 5;        // 0..7
  const int vcol = (tid & 31) * 4;  // 0..124

  for (int ch = 0; ch < L; ch += 32) {
    *(float4*)&Ps[lrow][lcol]      = *(const float4*)&Pb[(size_t)lrow * L + ch + lcol];
    *(float4*)&Ps[lrow + 32][lcol] = *(const float4*)&Pb[(size_t)(lrow + 32) * L + ch + lcol];
#pragma unroll
    for (int r0 = 0; r0 < 4; ++r0)
      *(float4*)&Vs[vrow + r0 * 8][vcol] =
          *(const float4*)&Vb[(size_t)(ch + vrow + r0 * 8) * D + vcol];
    __syncthreads();
#pragma unroll
    for (int kk = 0; kk < 32; kk += 4) {
      float4 a[4];
#pragma unroll
      for (int i = 0; i < 4; ++i) a[i] = *(const float4*)&Ps[ty + 16 * i][kk];
#pragma unroll
      for (int kkk = 0; kkk < 4; ++kkk) {
        float4 v0 = *(const float4*)&Vs[kk + kkk][tx * 8];
        float4 v1 = *(const float4*)&Vs[kk + kkk][tx * 8 + 4];
#pragma unroll
        for (int i = 0; i < 4; ++i) {
          float av = (kkk == 0) ? a[i].x : (kkk == 1) ? a[i].y
                    : (kkk == 2) ? a[i].z : a[i].w;
          acc[i][0] += av * v0.x; acc[i][1] += av * v0.y;
          acc[i][2] += av * v0.z; acc[i][3] += av * v0.w;
          acc[i][4] += av * v1.x; acc[i][5] += av * v1.y;
          acc[i][6] += av * v1.z; acc[i][7] += av * v1.w;
        }
      }
    }
    __syncthreads();
  }

  float* Ob = O + ((size_t)b * L + qt * 64) * D;
#pragma unroll
  for (int i = 0; i < 4; ++i) {
    float4 o0 = make_float4(acc[i][0], acc[i][1], acc[i][2], acc[i][3]);
    float4 o1 = make_float4(acc[i][4], acc[i][5], acc[i][6], acc[i][7]);
    *(float4*)&Ob[(size_t)(ty + 16 * i) * D + tx * 8]     = o0;
    *(float4*)&Ob[(size_t)(ty + 16 * i) * D + tx * 8 + 4] = o1;
  }
}

// ---------------------------------------------------------------------------
extern "C" void kernel_launch(void* const* d_in, const int* in_sizes, int n_in,
                              void* d_out, int out_size, void* d_ws, size_t ws_size,
                              hipStream_t stream) {
  const float* Q = (const float*)d_in[0];
  const float* K = (const float*)d_in[1];
  const float* V = (const float*)d_in[2];
  const float* R = (const float*)d_in[3];
  const float* M = (const float*)d_in[4];
  float* out  = (float*)d_out;
  float* attn = out + (size_t)BH * L * D;   // second tuple element
  float* lm   = (float*)d_ws;               // BH*L floats

  masklog_kernel<<<dim3((BH * L + 255) / 256), dim3(256), 0, stream>>>(M, lm, BH * L);
  qk_kernel<<<dim3(8, 8, BH), dim3(256), 0, stream>>>(Q, K, attn);
  rel_kernel<<<dim3(BH * LQ * LQ / 4), dim3(256), 0, stream>>>(R, Q, attn);
  softmax_kernel<<<dim3(BH * L / 4), dim3(256), 0, stream>>>(attn, lm);
  pv_kernel<<<dim3(8, BH), dim3(256), 0, stream>>>(attn, V, out);
}

// Round 2
// 556.473 us; speedup vs baseline: 1.4334x; 1.4334x over previous
//
#include <hip/hip_runtime.h>
#include <math.h>

#define BH 128
#define L 512
#define D 128
#define LQ 64

typedef short bf16x8 __attribute__((ext_vector_type(8)));
typedef float f32x4 __attribute__((ext_vector_type(4)));

__device__ inline short f2bf_t(float x) {   // truncating f32 -> bf16
  union { float f; unsigned u; } v; v.f = x;
  return (short)(v.u >> 16);
}
__device__ inline float bf2f(short h) {
  union { unsigned u; float f; } v;
  v.u = ((unsigned)(unsigned short)h) << 16;
  return v.f;
}

// split 8 floats into hi/lo bf16 and write 16B each to LDS
__device__ inline void split_write8(const float4 x0, const float4 x1,
                                    short* hi_dst, short* lo_dst) {
  float xs[8] = {x0.x, x0.y, x0.z, x0.w, x1.x, x1.y, x1.z, x1.w};
  union { bf16x8 v; short s[8]; } hv, lv;
#pragma unroll
  for (int j = 0; j < 8; ++j) {
    short h = f2bf_t(xs[j]);
    hv.s[j] = h;
    lv.s[j] = f2bf_t(xs[j] - bf2f(h));
  }
  *(bf16x8*)hi_dst = hv.v;
  *(bf16x8*)lo_dst = lv.v;
}

// ---------------------------------------------------------------------------
// Kernel 1: S[b] = Q[b] @ K[b]^T via split-bf16 MFMA (hh + hl + lh).
// grid (4,4,BH), block 256 (4 waves), 128x128 tile, K-chunks of 32.
// LDS fragment layout: frag f (16m x 32k) occupies 512 shorts; within frag,
// 16B granule slot = (m&15)*4 + (k>>3); lane l reads granule (l&15)*4+(l>>4).
// Staging writes are linear (thread t -> slots t, t+256) => conflict-free.
// ---------------------------------------------------------------------------
__global__ __launch_bounds__(256) void qk_mfma_kernel(const float* __restrict__ Q,
                                                      const float* __restrict__ Km,
                                                      float* __restrict__ S) {
  const int b  = blockIdx.z;
  const int qt = blockIdx.y;
  const int kt = blockIdx.x;
  __shared__ short Ah[8 * 512], Al[8 * 512], Bh[8 * 512], Bl[8 * 512];
  const int tid = threadIdx.x;
  const int lane = tid & 63;
  const int wave = tid >> 6;
  const int wr = wave >> 1, wc = wave & 1;

  const float* Qb = Q  + ((size_t)b * L + qt * 128) * D;
  const float* Kb = Km + ((size_t)b * L + kt * 128) * D;

  f32x4 acc[4][4];
#pragma unroll
  for (int i = 0; i < 4; ++i)
#pragma unroll
    for (int j = 0; j < 4; ++j) acc[i][j] = (f32x4){0.f, 0.f, 0.f, 0.f};

  const int fo = ((lane & 15) * 4 + (lane >> 4)) * 8;  // frag read offset (shorts)

  for (int c = 0; c < D; c += 32) {
#pragma unroll
    for (int s0 = 0; s0 < 2; ++s0) {
      const int s = tid + s0 * 256;       // granule slot 0..511
      const int m = s >> 2;               // row in 128-tile
      const int k = (s & 3) * 8;          // k within chunk
      float4 a0 = *(const float4*)&Qb[m * D + c + k];
      float4 a1 = *(const float4*)&Qb[m * D + c + k + 4];
      split_write8(a0, a1, &Ah[s * 8], &Al[s * 8]);
      float4 b0 = *(const float4*)&Kb[m * D + c + k];
      float4 b1 = *(const float4*)&Kb[m * D + c + k + 4];
      split_write8(b0, b1, &Bh[s * 8], &Bl[s * 8]);
    }
    __syncthreads();

    bf16x8 bhv[4], blv[4];
#pragma unroll
    for (int nt = 0; nt < 4; ++nt) {
      bhv[nt] = *(bf16x8*)&Bh[(wc * 4 + nt) * 512 + fo];
      blv[nt] = *(bf16x8*)&Bl[(wc * 4 + nt) * 512 + fo];
    }
#pragma unroll
    for (int mt = 0; mt < 4; ++mt) {
      bf16x8 ah = *(bf16x8*)&Ah[(wr * 4 + mt) * 512 + fo];
      bf16x8 al = *(bf16x8*)&Al[(wr * 4 + mt) * 512 + fo];
#pragma unroll
      for (int nt = 0; nt < 4; ++nt) {
        acc[mt][nt] = __builtin_amdgcn_mfma_f32_16x16x32_bf16(ah, bhv[nt], acc[mt][nt], 0, 0, 0);
        acc[mt][nt] = __builtin_amdgcn_mfma_f32_16x16x32_bf16(ah, blv[nt], acc[mt][nt], 0, 0, 0);
        acc[mt][nt] = __builtin_amdgcn_mfma_f32_16x16x32_bf16(al, bhv[nt], acc[mt][nt], 0, 0, 0);
      }
    }
    __syncthreads();
  }

  // C/D layout: col = lane&15, row = (lane>>4)*4 + reg
  float* Sb = S + ((size_t)b * L + qt * 128 + wr * 64) * L + kt * 128 + wc * 64;
  const int r0 = (lane >> 4) * 4, c0 = lane & 15;
#pragma unroll
  for (int mt = 0; mt < 4; ++mt)
#pragma unroll
    for (int nt = 0; nt < 4; ++nt)
#pragma unroll
      for (int j = 0; j < 4; ++j)
        Sb[(size_t)(mt * 16 + r0 + j) * L + nt * 16 + c0] = acc[mt][nt][j];
}

// ---------------------------------------------------------------------------
// Kernel 2: S[b, 448+q, 448+k] += dot(rel[b,q,k,:], Q[b,448+q,:])
// one wave per 2 dots (half-wave each), float4 loads = contiguous 1KB/wave.
// ---------------------------------------------------------------------------
__global__ __launch_bounds__(256) void rel_kernel(const float* __restrict__ R,
                                                  const float* __restrict__ Q,
                                                  float* __restrict__ S) {
  const int gw   = blockIdx.x * 4 + (threadIdx.x >> 6);  // k-pair index
  const int lane = threadIdx.x & 63;
  const int k2 = gw & 31;
  const int q  = (gw >> 5) & 63;
  const int b  = gw >> 11;
  const int k  = k2 * 2 + (lane >> 5);
  const int off = (lane & 31) * 4;
  const float* r  = R + (((size_t)b * LQ + q) * LQ + k) * D + off;
  const float* qr = Q + ((size_t)b * L + (L - LQ + q)) * D + off;
  float4 rv = *(const float4*)r;
  float4 qv = *(const float4*)qr;
  float s = rv.x * qv.x + rv.y * qv.y + rv.z * qv.z + rv.w * qv.w;
#pragma unroll
  for (int o = 16; o > 0; o >>= 1) s += __shfl_xor(s, o, 64);
  if ((lane & 31) == 0) {
    size_t idx = ((size_t)b * L + (L - LQ + q)) * L + (L - LQ + k);
    S[idx] += s;
  }
}

// ---------------------------------------------------------------------------
// Kernel 3a: lm = log(1 - mask)
// ---------------------------------------------------------------------------
__global__ void masklog_kernel(const float* __restrict__ mask,
                               float* __restrict__ lm, int n) {
  int i = blockIdx.x * blockDim.x + threadIdx.x;
  if (i < n) lm[i] = logf(1.0f - mask[i]);
}

// ---------------------------------------------------------------------------
// Kernel 3b: row softmax over k (512) with scale + logmask, in place.
// ---------------------------------------------------------------------------
__global__ __launch_bounds__(256) void softmax_kernel(float* __restrict__ S,
                                                      const float* __restrict__ lm) {
  const int grow = blockIdx.x * 4 + (threadIdx.x >> 6);
  const int lane = threadIdx.x & 63;
  const int b = grow >> 9;
  float* row = S + (size_t)grow * L;
  const float* lmb = lm + (size_t)b * L;
  const float scale = 0.08838834764831845f;  // 1/sqrt(128)

  float4 x0 = *(const float4*)&row[lane * 4];
  float4 x1 = *(const float4*)&row[256 + lane * 4];
  float4 m0 = *(const float4*)&lmb[lane * 4];
  float4 m1 = *(const float4*)&lmb[256 + lane * 4];
  x0.x = x0.x * scale + m0.x;  x0.y = x0.y * scale + m0.y;
  x0.z = x0.z * scale + m0.z;  x0.w = x0.w * scale + m0.w;
  x1.x = x1.x * scale + m1.x;  x1.y = x1.y * scale + m1.y;
  x1.z = x1.z * scale + m1.z;  x1.w = x1.w * scale + m1.w;

  float mx = fmaxf(fmaxf(fmaxf(x0.x, x0.y), fmaxf(x0.z, x0.w)),
                   fmaxf(fmaxf(x1.x, x1.y), fmaxf(x1.z, x1.w)));
#pragma unroll
  for (int o = 32; o > 0; o >>= 1) mx = fmaxf(mx, __shfl_xor(mx, o, 64));

  x0.x = __expf(x0.x - mx);  x0.y = __expf(x0.y - mx);
  x0.z = __expf(x0.z - mx);  x0.w = __expf(x0.w - mx);
  x1.x = __expf(x1.x - mx);  x1.y = __expf(x1.y - mx);
  x1.z = __expf(x1.z - mx);  x1.w = __expf(x1.w - mx);

  float sum = x0.x + x0.y + x0.z + x0.w + x1.x + x1.y + x1.z + x1.w;
#pragma unroll
  for (int o = 32; o > 0; o >>= 1) sum += __shfl_xor(sum, o, 64);
  const float inv = 1.0f / sum;

  x0.x *= inv; x0.y *= inv; x0.z *= inv; x0.w *= inv;
  x1.x *= inv; x1.y *= inv; x1.z *= inv; x1.w *= inv;
  *(float4*)&row[lane * 4]       = x0;
  *(float4*)&row[256 + lane * 4] = x1;
}

// ---------------------------------------------------------------------------
// Kernel 4: out[b] = P[b] (512x512) @ V[b] (512x128), split-bf16 MFMA.
// grid (4, BH), block 256, 128x128 tile, K-chunks of 32.
// V is transposed into LDS fragments at staging time. Granule-slot swizzle
// slot = (nr*4+kg) ^ ((nr>>2)&3) spreads the transposed b32 writes across
// banks (~2-way); reads use the same swizzle (still 64 distinct granules).
// ---------------------------------------------------------------------------
__global__ __launch_bounds__(256) void pv_mfma_kernel(const float* __restrict__ P,
                                                      const float* __restrict__ V,
                                                      float* __restrict__ O) {
  const int b  = blockIdx.y;
  const int qt = blockIdx.x;
  __shared__ short Ph[8 * 512], Pl[8 * 512];
  __shared__ short Vh[8 * 528], Vl[8 * 528];   // frag stride 528 shorts (pad 32B)
  const int tid = threadIdx.x;
  const int lane = tid & 63;
  const int wave = tid >> 6;
  const int wr = wave >> 1, wc = wave & 1;

  const float* Pb = P + ((size_t)b * L + qt * 128) * L;
  const float* Vb = V + (size_t)b * L * D;

  f32x4 acc[4][4];
#pragma unroll
  for (int i = 0; i < 4; ++i)
#pragma unroll
    for (int j = 0; j < 4; ++j) acc[i][j] = (f32x4){0.f, 0.f, 0.f, 0.f};

  const int d4 = tid & 31;       // V: float4 column group (d = d4*4+j)
  const int p0 = tid >> 5;       // V: k-pair base
  const int nt_s = d4 >> 2;      // V: frag index being written
  const int fo = ((lane & 15) * 4 + (lane >> 4)) * 8;
  const int slot_r = (((lane & 15) * 4 + (lane >> 4)) ^ (((lane & 15) >> 2) & 3));
  const int fov = slot_r * 8;

  for (int ch = 0; ch < L; ch += 32) {
    // stage P rows (linear granules, conflict-free)
#pragma unroll
    for (int s0 = 0; s0 < 2; ++s0) {
      const int s = tid + s0 * 256;
      const int m = s >> 2;
      const int k = (s & 3) * 8;
      float4 a0 = *(const float4*)&Pb[(size_t)m * L + ch + k];
      float4 a1 = *(const float4*)&Pb[(size_t)m * L + ch + k + 4];
      split_write8(a0, a1, &Ph[s * 8], &Pl[s * 8]);
    }
    // stage V transposed (paired-k b32 writes, swizzled granules)
#pragma unroll
    for (int pp = 0; pp < 2; ++pp) {
      const int p = p0 + pp * 8;          // 0..15
      const int k0 = 2 * p;
      const int kg = p >> 2, kr = 2 * (p & 3);
      float4 v0 = *(const float4*)&Vb[(size_t)(ch + k0) * D + d4 * 4];
      float4 v1 = *(const float4*)&Vb[(size_t)(ch + k0 + 1) * D + d4 * 4];
      float a0[4] = {v0.x, v0.y, v0.z, v0.w};
      float a1[4] = {v1.x, v1.y, v1.z, v1.w};
#pragma unroll
      for (int j = 0; j < 4; ++j) {
        const int nr = (d4 & 3) * 4 + j;
        const int slot = (nr * 4 + kg) ^ ((nr >> 2) & 3);
        const int idx = nt_s * 528 + slot * 8 + kr;
        short ha = f2bf_t(a0[j]), hb = f2bf_t(a1[j]);
        short la = f2bf_t(a0[j] - bf2f(ha)), lb = f2bf_t(a1[j] - bf2f(hb));
        *(unsigned*)&Vh[idx] = (unsigned)(unsigned short)ha |
                               ((unsigned)(unsigned short)hb << 16);
        *(unsigned*)&Vl[idx] = (unsigned)(unsigned short)la |
                               ((unsigned)(unsigned short)lb << 16);
      }
    }
    __syncthreads();

    bf16x8 bhv[4], blv[4];
#pragma unroll
    for (int nt = 0; nt < 4; ++nt) {
      bhv[nt] = *(bf16x8*)&Vh[(wc * 4 + nt) * 528 + fov];
      blv[nt] = *(bf16x8*)&Vl[(wc * 4 + nt) * 528 + fov];
    }
#pragma unroll
    for (int mt = 0; mt < 4; ++mt) {
      bf16x8 ah = *(bf16x8*)&Ph[(wr * 4 + mt) * 512 + fo];
      bf16x8 al = *(bf16x8*)&Pl[(wr * 4 + mt) * 512 + fo];
#pragma unroll
      for (int nt = 0; nt < 4; ++nt) {
        acc[mt][nt] = __builtin_amdgcn_mfma_f32_16x16x32_bf16(ah, bhv[nt], acc[mt][nt], 0, 0, 0);
        acc[mt][nt] = __builtin_amdgcn_mfma_f32_16x16x32_bf16(ah, blv[nt], acc[mt][nt], 0, 0, 0);
        acc[mt][nt] = __builtin_amdgcn_mfma_f32_16x16x32_bf16(al, bhv[nt], acc[mt][nt], 0, 0, 0);
      }
    }
    __syncthreads();
  }

  float* Ob = O + ((size_t)b * L + qt * 128 + wr * 64) * D + wc * 64;
  const int r0 = (lane >> 4) * 4, c0 = lane & 15;
#pragma unroll
  for (int mt = 0; mt < 4; ++mt)
#pragma unroll
    for (int nt = 0; nt < 4; ++nt)
#pragma unroll
      for (int j = 0; j < 4; ++j)
        Ob[(size_t)(mt * 16 + r0 + j) * D + nt * 16 + c0] = acc[mt][nt][j];
}

// ---------------------------------------------------------------------------
extern "C" void kernel_launch(void* const* d_in, const int* in_sizes, int n_in,
                              void* d_out, int out_size, void* d_ws, size_t ws_size,
                              hipStream_t stream) {
  const float* Q = (const float*)d_in[0];
  const float* K = (const float*)d_in[1];
  const float* V = (const float*)d_in[2];
  const float* R = (const float*)d_in[3];
  const float* M = (const float*)d_in[4];
  float* out  = (float*)d_out;
  float* attn = out + (size_t)BH * L * D;
  float* lm   = (float*)d_ws;

  masklog_kernel<<<dim3((BH * L + 255) / 256), dim3(256), 0, stream>>>(M, lm, BH * L);
  qk_mfma_kernel<<<dim3(4, 4, BH), dim3(256), 0, stream>>>(Q, K, attn);
  rel_kernel<<<dim3(BH * LQ * LQ / 8), dim3(256), 0, stream>>>(R, Q, attn);
  softmax_kernel<<<dim3(BH * L / 4), dim3(256), 0, stream>>>(attn, lm);
  pv_mfma_kernel<<<dim3(4, BH), dim3(256), 0, stream>>>(attn, V, out);
}